// Round 3
// baseline (894.962 us; speedup 1.0000x reference)
//
#include <hip/hip_runtime.h>

// Round 6: occupancy to the cap + launch fusion.
//  - ONE fused kernel (spatial blocks 0..8191, temporal 8192..14335,
//    temporal-edge 14336..14463), 1024 threads (16 waves), 67KB LDS ->
//    2 blocks/CU = 32 waves/CU (100% cap, was 50%). VGPR<=64 enforced.
//  - temporal grid de-waste: 6 full n-groups per b (n 0..47, NO guards) +
//    128 edge blocks each covering n=48 for 8 consecutive b (same
//    block-diagonal 8x8 attention, different row map). 7168 -> 6272 blocks.
//  - spatial tail blocks overlap temporal head blocks (single launch).
// mfma_f32_16x16x32_bf16: A[m=lane&15][k=quad*8+j], B[n=lane&15][k=quad*8+j],
//                         C/D: col=lane&15, row=quad*4+reg
typedef __bf16 bf16x2 __attribute__((ext_vector_type(2)));
typedef __bf16 bf16x4 __attribute__((ext_vector_type(4)));
typedef __bf16 bf16x8 __attribute__((ext_vector_type(8)));
typedef float f32x4 __attribute__((ext_vector_type(4)));
#define MFMA __builtin_amdgcn_mfma_f32_16x16x32_bf16

#define SCALE 0.17677669529663687f   // 1/sqrt(32)
#define QS2 200  // Q|K LDS row stride (bf16); 400B rows
#define VS 72    // VT row stride (bf16); 36 dwords = 4 mod 8 -> b128 conflict-free
#define PS 72    // P row stride (bf16)
#define CS 104   // xt/ctx row stride (bf16); 52 dwords = 4 mod 8
#define NT 1024
#define WAVES 16

__device__ __forceinline__ bf16x4 cvt4(const float* p) {
  bf16x4 v;
  float4 f = *(const float4*)p;
  v[0] = (__bf16)f.x; v[1] = (__bf16)f.y; v[2] = (__bf16)f.z; v[3] = (__bf16)f.w;
  return v;
}
__device__ __forceinline__ bf16x4 bz4() {
  bf16x4 z;
  for (int i = 0; i < 4; ++i) z[i] = (__bf16)0.f;
  return z;
}

// ---- K0: transpose+convert weights into ws: WqT[288x96] | WspT[96x96] | WtmT[96x96] ----
__global__ __launch_bounds__(256) void k_transpose(const float* __restrict__ Wq,
    const float* __restrict__ Wsp, const float* __restrict__ Wtm,
    __bf16* __restrict__ ws) {
  const int which = blockIdx.x, tid = threadIdx.x;
  if (which == 0) {
    for (int idx = tid; idx < 27648; idx += 256) {
      int n = idx / 96, k = idx % 96;
      ws[idx] = (__bf16)Wq[k * 288 + n];          // WqT[n][k] = Wq[k][n]
    }
  } else {
    const float* src = (which == 1) ? Wsp : Wtm;
    __bf16* dst = ws + 27648 + (which - 1) * 9216;
    for (int idx = tid; idx < 9216; idx += 256) {
      int n = idx / 96, k = idx % 96;
      dst[idx] = (__bf16)src[k * 96 + n];
    }
  }
}

// ---- fused main kernel ----
// smem regions (bytes):
//   [0,25600)      qk (Q|K, 64 x QS2)      -> ctx (64 x CS) after scores
//   [25600,53248)  xt (64 x CS, phase A)   -> P (192 x PS) from phase B
//   [53248,67072)  VT (96 x VS)
__global__ __launch_bounds__(1024, 8) void k_fused(const float* __restrict__ x,
    const __bf16* __restrict__ WqT, const float* __restrict__ qkv_b,
    const float* __restrict__ mask,
    const __bf16* __restrict__ WspT, const float* __restrict__ bsp,
    const __bf16* __restrict__ WtmT, const float* __restrict__ btm,
    float* __restrict__ out) {
  __shared__ __align__(16) char smem[67072];
  __bf16* qk  = (__bf16*)(smem);
  __bf16* ctx = (__bf16*)(smem);
  __bf16* xt  = (__bf16*)(smem + 25600);
  __bf16* P   = (__bf16*)(smem + 25600);
  __bf16* VT  = (__bf16*)(smem + 53248);

  const int tid = threadIdx.x;
  const int wave = tid >> 6, lane = tid & 63, lr = lane & 15, quad = lane >> 4;
  const int bid = blockIdx.x;
  const bool is_sp = (bid < 8192);

  long rbase = 0; int b = 0, n0 = 0, b0 = 0; bool edge = false;
  if (is_sp) {
    rbase = (long)bid * 49;                       // bt = bid
  } else if (bid < 14336) {
    int idx = bid - 8192; b = idx / 6; n0 = (idx % 6) * 8;   // n 0..47, all valid
  } else {
    edge = true; b0 = (bid - 14336) * 8;          // n = 48 for b0..b0+7
  }

  // ---- phase A: stage x (fp32->bf16); qkv MFMA with global-B ----
  for (int v = tid; v < 1536; v += NT) {          // 64 rows x 24 float4
    int s = v / 24, c = (v % 24) * 4;
    bf16x4 val;
    if (is_sp) {
      val = bz4();
      if (s < 49) val = cvt4(&x[(rbase + s) * 96 + c]);
    } else {
      long gr = edge ? ((long)((b0 + (s >> 3)) * 8 + (s & 7)) * 49 + 48)
                     : ((long)(b * 8 + (s & 7)) * 49 + n0 + (s >> 3));
      val = cvt4(&x[gr * 96 + c]);
    }
    *(bf16x4*)&xt[s * CS + c] = val;
  }
  __syncthreads();
  {
    bf16x8 afr[4][3];                             // A fragments in regs
    for (int rt = 0; rt < 4; ++rt)
      for (int ks = 0; ks < 3; ++ks)
        afr[rt][ks] = *(const bf16x8*)&xt[(rt * 16 + lr) * CS + ks * 32 + quad * 8];
    for (int ct = wave; ct < 18; ct += WAVES) {   // B fragments straight from L2
      const __bf16* wrow = &WqT[(ct * 16 + lr) * 96 + quad * 8];
      bf16x8 b0f = *(const bf16x8*)&wrow[0];
      bf16x8 b1f = *(const bf16x8*)&wrow[32];
      bf16x8 b2f = *(const bf16x8*)&wrow[64];
      int col = ct * 16 + lr;
      float bv = qkv_b[col];
      for (int rt = 0; rt < 4; ++rt) {
        f32x4 acc = {0.f, 0.f, 0.f, 0.f};
        acc = MFMA(afr[rt][0], b0f, acc, 0, 0, 0);
        acc = MFMA(afr[rt][1], b1f, acc, 0, 0, 0);
        acc = MFMA(afr[rt][2], b2f, acc, 0, 0, 0);
        if (ct < 12) {                            // Q|K -> qk rows
          for (int i = 0; i < 4; ++i)
            qk[(rt * 16 + quad * 4 + i) * QS2 + col] = (__bf16)(acc[i] + bv);
        } else {                                  // V -> VT transposed, packed 4B
          int d = col - 192;
          __bf16* vp = &VT[d * VS + rt * 16 + quad * 4];
          bf16x2 lo; lo[0] = (__bf16)(acc[0] + bv); lo[1] = (__bf16)(acc[1] + bv);
          bf16x2 hi; hi[0] = (__bf16)(acc[2] + bv); hi[1] = (__bf16)(acc[3] + bv);
          *(bf16x2*)&vp[0] = lo;
          *(bf16x2*)&vp[2] = hi;
        }
      }
    }
  }
  __syncthreads();                                // xt dead; P takes its region

  // ---- phase B: scores + softmax -> P ----
  if (is_sp) {
    // wave (=task, 12 of 16) owns (h = wave>>2, rt = wave&3); m>=49 -> -1e30.
    if (wave < 12) {
      const int rt = wave & 3, h = wave >> 2;
      const int nb = rt * 16 + quad * 4;
      const float* mrow = mask + (long)(bid & 63) * 2401;
      float mv[4][4];
      for (int ct = 0; ct < 4; ++ct) {
        int m = ct * 16 + lr;
        int mm = (m < 49) ? m : 48;
        for (int i = 0; i < 4; ++i) {
          int nn = (nb + i < 49) ? nb + i : 48;
          mv[ct][i] = mrow[nn * 49 + mm];
        }
      }
      bf16x8 qf = *(const bf16x8*)&qk[(rt * 16 + lr) * QS2 + h * 32 + quad * 8];
      float sv[4][4];
      for (int ct = 0; ct < 4; ++ct) {
        bf16x8 kf = *(const bf16x8*)&qk[(ct * 16 + lr) * QS2 + 96 + h * 32 + quad * 8];
        f32x4 acc = {0.f, 0.f, 0.f, 0.f};
        acc = MFMA(qf, kf, acc, 0, 0, 0);
        int m = ct * 16 + lr;
        for (int i = 0; i < 4; ++i)
          sv[ct][i] = (m < 49) ? (acc[i] * SCALE + mv[ct][i]) : -1e30f;
      }
      for (int i = 0; i < 4; ++i) {
        float mx = fmaxf(fmaxf(sv[0][i], sv[1][i]), fmaxf(sv[2][i], sv[3][i]));
        mx = fmaxf(mx, __shfl_xor(mx, 1));
        mx = fmaxf(mx, __shfl_xor(mx, 2));
        mx = fmaxf(mx, __shfl_xor(mx, 4));
        mx = fmaxf(mx, __shfl_xor(mx, 8));
        float e0 = __expf(sv[0][i] - mx), e1 = __expf(sv[1][i] - mx);
        float e2 = __expf(sv[2][i] - mx), e3 = __expf(sv[3][i] - mx);
        float sum = e0 + e1 + e2 + e3;
        sum += __shfl_xor(sum, 1);
        sum += __shfl_xor(sum, 2);
        sum += __shfl_xor(sum, 4);
        sum += __shfl_xor(sum, 8);
        float inv = 1.f / sum;
        __bf16* Pr = &P[(h * 64 + nb + i) * PS + lr];
        Pr[0]  = (__bf16)(e0 * inv);
        Pr[16] = (__bf16)(e1 * inv);
        Pr[32] = (__bf16)(e2 * inv);
        Pr[48] = (__bf16)(e3 * inv);
      }
    }
  } else {
    // block-diagonal 8x8 attn: wave (=task, 12 of 16) owns (h = wave>>2, p = wave&3)
    if (wave < 12) {
      const bool useful = (((lane & 15) >> 3) == (lane >> 5));
      int p = wave & 3, h = wave >> 2;
      bf16x8 qf = *(const bf16x8*)&qk[(p * 16 + lr) * QS2 + h * 32 + quad * 8];
      bf16x8 kf = *(const bf16x8*)&qk[(p * 16 + lr) * QS2 + 96 + h * 32 + quad * 8];
      f32x4 acc = {0.f, 0.f, 0.f, 0.f};
      acc = MFMA(qf, kf, acc, 0, 0, 0);
      for (int rr = 0; rr < 4; ++rr) {
        float s = acc[rr] * SCALE;
        float mx = s;
        mx = fmaxf(mx, __shfl_xor(mx, 1));
        mx = fmaxf(mx, __shfl_xor(mx, 2));
        mx = fmaxf(mx, __shfl_xor(mx, 4));
        float e = __expf(s - mx);
        float sum = e;
        sum += __shfl_xor(sum, 1);
        sum += __shfl_xor(sum, 2);
        sum += __shfl_xor(sum, 4);
        float pv = useful ? (e / sum) : 0.f;
        int row = h * 64 + p * 16 + quad * 4 + rr;
        P[row * PS + p * 16 + (lane & 15)] = (__bf16)pv;
        P[row * PS + (p ^ 1) * 16 + (lane & 15)] = (__bf16)0.f;
      }
    }
  }
  __syncthreads();                                // qk dead; ctx takes its region

  // ---- phase C: PV -> ctx ----
  if (is_sp) {
    for (int tile = wave; tile < 24; tile += WAVES) {
      int h = tile / 8, rt = (tile / 2) & 3, dt = tile & 1;
      f32x4 acc = {0.f, 0.f, 0.f, 0.f};
      for (int ks = 0; ks < 2; ++ks) {
        bf16x8 a  = *(const bf16x8*)&P[(h * 64 + rt * 16 + lr) * PS + ks * 32 + quad * 8];
        bf16x8 bb = *(const bf16x8*)&VT[(h * 32 + dt * 16 + lr) * VS + ks * 32 + quad * 8];
        acc = MFMA(a, bb, acc, 0, 0, 0);
      }
      for (int i = 0; i < 4; ++i)
        ctx[(rt * 16 + quad * 4 + i) * CS + h * 32 + dt * 16 + lr] = (__bf16)acc[i];
    }
  } else {
    for (int task = wave; task < 24; task += WAVES) {
      int h = task >> 3, pt = (task >> 1) & 3, dh = task & 1;
      bf16x8 a  = *(const bf16x8*)&P[(h * 64 + pt * 16 + lr) * PS + (pt >> 1) * 32 + quad * 8];
      bf16x8 bb = *(const bf16x8*)&VT[(h * 32 + dh * 16 + lr) * VS + (pt >> 1) * 32 + quad * 8];
      f32x4 acc = {0.f, 0.f, 0.f, 0.f};
      acc = MFMA(a, bb, acc, 0, 0, 0);
      for (int i = 0; i < 4; ++i)
        ctx[(pt * 16 + quad * 4 + i) * CS + h * 32 + dh * 16 + lr] = (__bf16)acc[i];
    }
  }
  __syncthreads();

  // ---- phase D: proj -> out, B fragments from L2 ----
  {
    const __bf16* Wp = is_sp ? WspT : WtmT;
    const float* bpv = is_sp ? bsp : btm;
    float* outp = is_sp ? (out + 38535168) : out; // x_sp | x_t halves
    for (int tile = wave; tile < 24; tile += WAVES) {
      int rt = tile / 6, ct = tile % 6;
      int col = ct * 16 + lr;
      const __bf16* wrow = &Wp[col * 96 + quad * 8];
      f32x4 acc = {0.f, 0.f, 0.f, 0.f};
      for (int ks = 0; ks < 3; ++ks) {
        bf16x8 a  = *(const bf16x8*)&ctx[(rt * 16 + lr) * CS + ks * 32 + quad * 8];
        bf16x8 bb = *(const bf16x8*)&wrow[ks * 32];
        acc = MFMA(a, bb, acc, 0, 0, 0);
      }
      float bv = bpv[col];
      for (int i = 0; i < 4; ++i) {
        int s = rt * 16 + quad * 4 + i;
        if (is_sp) {
          if (s < 49) outp[(rbase + s) * 96 + col] = acc[i] + bv;
        } else {
          long gr = edge ? ((long)((b0 + (s >> 3)) * 8 + (s & 7)) * 49 + 48)
                         : ((long)(b * 8 + (s & 7)) * 49 + n0 + (s >> 3));
          outp[gr * 96 + col] = acc[i] + bv;
        }
      }
    }
  }
}

extern "C" void kernel_launch(void* const* d_in, const int* in_sizes, int n_in,
                              void* d_out, int out_size, void* d_ws, size_t ws_size,
                              hipStream_t stream) {
  const float* x         = (const float*)d_in[0];
  const float* mask      = (const float*)d_in[1];
  const float* qkv_w     = (const float*)d_in[2];
  const float* qkv_b     = (const float*)d_in[3];
  const float* proj_sp_w = (const float*)d_in[4];
  const float* proj_sp_b = (const float*)d_in[5];
  const float* proj_t_w  = (const float*)d_in[6];
  const float* proj_t_b  = (const float*)d_in[7];
  float* out = (float*)d_out;                      // [x_t | x_sp], each 401408*96
  __bf16* wsb = (__bf16*)d_ws;                     // 92,160 B used

  const __bf16* WqT  = wsb;                        // 288x96
  const __bf16* WspT = wsb + 27648;                // 96x96
  const __bf16* WtmT = wsb + 36864;                // 96x96

  k_transpose<<<dim3(3), dim3(256), 0, stream>>>(qkv_w, proj_sp_w, proj_t_w, wsb);
  // 8192 spatial + 1024*6 temporal + 128 temporal-edge (n=48) blocks
  k_fused<<<dim3(14464), dim3(1024), 0, stream>>>(x, WqT, qkv_b, mask,
                                                  WspT, proj_sp_b,
                                                  WtmT, proj_t_b, out);
}